// Round 8
// baseline (136.525 us; speedup 1.0000x reference)
//
#include <hip/hip_runtime.h>

// R8 — INSTRUMENTED PROBE (regression expected; revert next round).
// Purpose: the matcher (~55us) hides below the ~59us fill cut-line in top-5,
// so R7's streaming-store effect on FETCH was unobservable. This round runs
// the row loop 1.5x (rows 0-15 + rows 0-7 again, idempotent, clobber-separated)
// with the sc0sc1nt stores KEPT -> matcher ~80-85us -> top-1 dispatch row.
// Pre-committed readout:
//   FETCH ~6-10MB  -> policy bits eliminated write-allocate; time NOT traffic-
//                     bound -> attack store concurrency/overlap next.
//   FETCH ~140+MB  -> flat-store policy bits useless -> try MUBUF buffer_store
//                     (the rocclr fill's path) or read-prefetch phase split.
// Also reads WRITE amplification and VALUBusy for the near-real kernel.

#define NC 91
#define TT 1600
#define T4 (TT / 4)         // 400 float4 columns
#define ROWS 16
#define NTHREADS 448
#define TABN (ROWS * NC)    // 1456 floats
#define TAB4 (TABN / 4)     // 364 float4

typedef float vfloat4 __attribute__((ext_vector_type(4)));

__device__ __forceinline__ float focal_tab(float x) {
    const float p = __builtin_amdgcn_rcpf(1.f + __expf(-x));  // sigmoid
    const float omp = 1.f - p;
    const float neg = 0.75f * p * p * (-__logf(omp + 1e-8f));
    const float pos = 0.25f * omp * omp * (-__logf(p + 1e-8f));
    return 2.f * (pos - neg) + 2.f;   // fold COST_CLASS and giou's "+1"
}

__device__ __forceinline__ void store_stream(vfloat4* addr, vfloat4 v) {
    asm volatile("global_store_dwordx4 %0, %1, off sc0 sc1 nt"
                 :: "v"(addr), "v"(v)
                 : "memory");
}

__global__ __launch_bounds__(NTHREADS, 4) void matcher_kernel(
    const float* __restrict__ logits,      // [N, 91]
    const float4* __restrict__ pboxes,     // [N] (cx,cy,w,h)
    const int4* __restrict__ tids,         // [T/4]
    const float4* __restrict__ tboxes,     // [T] (cx,cy,w,h)
    vfloat4* __restrict__ out)             // [N, T/4]
{
    __shared__ float tab[TABN];            // flat [ROWS][NC]

    const int n0 = blockIdx.x * ROWS;
    const int tid = threadIdx.x;
    const bool active = (tid < T4);

    // --- issue t-side vector loads FIRST; latency hides under tab build ---
    int4 ids = {0, 0, 0, 0};
    float4 tb[4];
    if (active) {
        ids = tids[tid];
#pragma unroll
        for (int j = 0; j < 4; ++j) tb[j] = tboxes[tid * 4 + j];
    }

    // --- prologue: coalesced float4 logits -> elementwise focal -> LDS ---
    if (tid < TAB4) {
        const float4 v = *reinterpret_cast<const float4*>(
            logits + (size_t)n0 * NC + 4 * (size_t)tid);
        float4 o;
        o.x = focal_tab(v.x);
        o.y = focal_tab(v.y);
        o.z = focal_tab(v.z);
        o.w = focal_tab(v.w);
        *reinterpret_cast<float4*>(&tab[4 * tid]) = o;
    }
    __syncthreads();

    if (!active) return;

    const int idv[4] = {ids.x, ids.y, ids.z, ids.w};
    float tx0[4], ty0[4], tx1[4], ty1[4];
#pragma unroll
    for (int j = 0; j < 4; ++j) {
        tx0[j] = tb[j].x - 0.5f * tb[j].z;
        ty0[j] = tb[j].y - 0.5f * tb[j].w;
        tx1[j] = tb[j].x + 0.5f * tb[j].z;
        ty1[j] = tb[j].y + 0.5f * tb[j].w;
    }

    // ===== pass 1: all 16 rows; pass 2: rows 0-7 again (idempotent) =====
    for (int rep = 0; rep < 2; ++rep) {
        const int rmax = rep ? (ROWS / 2) : ROWS;
        for (int r = 0; r < rmax; ++r) {
            const float4 b = pboxes[n0 + r];   // block-uniform -> s_load
            const float pcx = b.x, pcy = b.y, pw = b.z, ph = b.w;
            const float px0 = pcx - 0.5f * pw, py0 = pcy - 0.5f * ph;
            const float px1 = pcx + 0.5f * pw, py1 = pcy + 0.5f * ph;
            const float pa  = pw * ph;
            vfloat4 res;
#pragma unroll
            for (int j = 0; j < 4; ++j) {
                const float tw = tx1[j] - tx0[j];
                const float th = ty1[j] - ty0[j];
                const float iwr = fminf(px1, tx1[j]) - fmaxf(px0, tx0[j]);
                const float ihr = fminf(py1, ty1[j]) - fmaxf(py0, ty0[j]);
                const float inter = fmaxf(iwr, 0.f) * fmaxf(ihr, 0.f);
                const float uni = pa + tw * th - inter;
                const float ew = (pw + tw) - iwr;
                const float eh = (ph + th) - ihr;
                const float ae = ew * eh;
                const float tcx = tx0[j] + 0.5f * tw;
                const float tcy = ty0[j] + 0.5f * th;
                const float l1 = fabsf(pcx - tcx) + fabsf(pcy - tcy)
                               + fabsf(pw - tw) + fabsf(ph - th);
                res[j] = 5.f * l1 + tab[r * NC + idv[j]]
                       - 2.f * inter * __builtin_amdgcn_rcpf(uni)
                       - 2.f * uni * __builtin_amdgcn_rcpf(ae);
            }
            store_stream(&out[(size_t)(n0 + r) * T4 + tid], res);
        }
        // keep the repeat pass alive (stores of identical values)
        asm volatile("" ::: "memory");
    }
}

extern "C" void kernel_launch(void* const* d_in, const int* in_sizes, int n_in,
                              void* d_out, int out_size, void* d_ws, size_t ws_size,
                              hipStream_t stream) {
    const float* logits  = (const float*)d_in[0];
    const float4* pboxes = (const float4*)d_in[1];
    const int4* tids     = (const int4*)d_in[2];
    const float4* tboxes = (const float4*)d_in[3];
    vfloat4* out = (vfloat4*)d_out;
    const int N = in_sizes[1] / 4;  // 14400 rows
    matcher_kernel<<<N / ROWS, NTHREADS, 0, stream>>>(logits, pboxes, tids, tboxes, out);
}

// Round 9
// 120.538 us; speedup vs baseline: 1.1326x; 1.1326x over previous
//
#include <hip/hip_runtime.h>

// HungarianMatcher cost matrix: C[n,t] = 5*L1(box_n,box_t) + 2*(pos-neg)[n,id_t] - 2*GIoU(n,t)
// bs=16, nq=900 -> N=14400 rows; T=1600 targets; nc=91 classes.
// R9: eliminate the per-row LDS gather from the steady-state loop.
// Evidence: R6/R8 probes -> marginal plain pass 129us vs streaming 29us (sc0sc1nt
// kills write-allocate traffic), yet 1x dur_us pinned ~122 for BOTH -> at 1x the
// matcher (~45us vs ~20us roofline) is latency-stall-bound (VALU 12%, HBM 37%),
// not traffic-bound. Last untested mechanism: 64 scalar tab gathers/thread
// (ds_read ~120cy) threaded through the row loop.
// Fix: idv[] is ROW-INVARIANT -> transpose table to tab_t[class][row] (row dim
// padded 16->20 floats: spreads banks, keeps 16B align), prefetch each thread's
// 4 class-columns with 16x ds_read_b128 up-front into 64 VGPRs. Main loop is
// then pure VALU + stores: no LDS, no lgkm waits, full cross-row ILP.
// VGPR ~110 < 128 cap of (448,4) (spill signature would be +12us, cf. R2).
// Predicted: matcher ~45 -> ~30, dur_us 122 -> ~105-112. If neutral: declare
// structural floor (fill 58 + harness ~17 + matcher near-roofline).

#define NC 91
#define TT 1600
#define T4 (TT / 4)         // 400 float4 columns
#define ROWS 16
#define RPAD 20             // padded row-dim: 80B stride, 16B-aligned, banks spread
#define NTHREADS 448
#define TABN (ROWS * NC)    // 1456 logical floats
#define TAB4 (TABN / 4)     // 364 float4 loads in prologue

typedef float vfloat4 __attribute__((ext_vector_type(4)));

__device__ __forceinline__ float focal_tab(float x) {
    const float p = __builtin_amdgcn_rcpf(1.f + __expf(-x));  // sigmoid
    const float omp = 1.f - p;
    const float neg = 0.75f * p * p * (-__logf(omp + 1e-8f));
    const float pos = 0.25f * omp * omp * (-__logf(p + 1e-8f));
    return 2.f * (pos - neg) + 2.f;   // fold COST_CLASS and giou's "+1"
}

__global__ __launch_bounds__(NTHREADS, 4) void matcher_kernel(
    const float* __restrict__ logits,      // [N, 91]
    const float4* __restrict__ pboxes,     // [N] (cx,cy,w,h)
    const int4* __restrict__ tids,         // [T/4]
    const float4* __restrict__ tboxes,     // [T] (cx,cy,w,h)
    vfloat4* __restrict__ out)             // [N, T/4]
{
    __shared__ __align__(16) float tab_t[NC * RPAD];   // [class][row(padded)]

    const int n0 = blockIdx.x * ROWS;
    const int tid = threadIdx.x;
    const bool active = (tid < T4);

    // --- issue t-side vector loads FIRST; latency hides under tab build ---
    int4 ids = {0, 0, 0, 0};
    float4 tb[4];
    if (active) {
        ids = tids[tid];
#pragma unroll
        for (int j = 0; j < 4; ++j) tb[j] = tboxes[tid * 4 + j];
    }

    // --- prologue: coalesced float4 logits -> focal -> TRANSPOSED LDS ---
    if (tid < TAB4) {
        const float4 v = *reinterpret_cast<const float4*>(
            logits + (size_t)n0 * NC + 4 * (size_t)tid);
        const float vv[4] = {v.x, v.y, v.z, v.w};
#pragma unroll
        for (int k = 0; k < 4; ++k) {
            const int e = 4 * tid + k;      // flat [16][91] element
            const int r = e / NC;           // magic-mul div by 91
            const int c = e - r * NC;
            tab_t[c * RPAD + r] = focal_tab(vv[k]);
        }
    }
    __syncthreads();

    if (!active) return;

    const int idv[4] = {ids.x, ids.y, ids.z, ids.w};
    // keep ONLY corners in VGPRs (16 regs of target state)
    float tx0[4], ty0[4], tx1[4], ty1[4];
#pragma unroll
    for (int j = 0; j < 4; ++j) {
        tx0[j] = tb[j].x - 0.5f * tb[j].z;
        ty0[j] = tb[j].y - 0.5f * tb[j].w;
        tx1[j] = tb[j].x + 0.5f * tb[j].z;
        ty1[j] = tb[j].y + 0.5f * tb[j].w;
    }

    // --- prefetch ALL tab values for this thread's 4 ids: 16x ds_read_b128 ---
    // tv[j][q][k] = tab value for target-slot j, row 4q+k. 64 VGPRs, one-time.
    vfloat4 tv[4][4];
#pragma unroll
    for (int j = 0; j < 4; ++j) {
#pragma unroll
        for (int q = 0; q < 4; ++q)
            tv[j][q] = *reinterpret_cast<const vfloat4*>(
                &tab_t[idv[j] * RPAD + 4 * q]);
    }

    // --- main loop: pure VALU + stores; no LDS, no lgkm waits ---
#pragma unroll
    for (int r = 0; r < ROWS; ++r) {
        // block-uniform address -> scalar load, lives in SGPRs (no VGPR cost)
        const float4 b = pboxes[n0 + r];
        const float pcx = b.x, pcy = b.y, pw = b.z, ph = b.w;
        const float px0 = pcx - 0.5f * pw, py0 = pcy - 0.5f * ph;
        const float px1 = pcx + 0.5f * pw, py1 = pcy + 0.5f * ph;
        const float pa  = pw * ph;
        vfloat4 res;
#pragma unroll
        for (int j = 0; j < 4; ++j) {
            const float tw = tx1[j] - tx0[j];
            const float th = ty1[j] - ty0[j];
            // intersection (raw, may be negative)
            const float iwr = fminf(px1, tx1[j]) - fmaxf(px0, tx0[j]);
            const float ihr = fminf(py1, ty1[j]) - fmaxf(py0, ty0[j]);
            const float inter = fmaxf(iwr, 0.f) * fmaxf(ihr, 0.f);
            const float uni = pa + tw * th - inter;
            // enclosing box via min+max identity (clamp is a no-op: w,h>=0)
            const float ew = (pw + tw) - iwr;
            const float eh = (ph + th) - ihr;
            const float ae = ew * eh;
            const float tcx = tx0[j] + 0.5f * tw;
            const float tcy = ty0[j] + 0.5f * th;
            const float l1 = fabsf(pcx - tcx) + fabsf(pcy - tcy)
                           + fabsf(pw - tw) + fabsf(ph - th);
            // static indices (r compile-time via full unroll) -> stays in regs
            res[j] = 5.f * l1 + tv[j][r >> 2][r & 3]
                   - 2.f * inter * __builtin_amdgcn_rcpf(uni)
                   - 2.f * uni * __builtin_amdgcn_rcpf(ae);
        }
        out[(size_t)(n0 + r) * T4 + tid] = res;
    }
}

extern "C" void kernel_launch(void* const* d_in, const int* in_sizes, int n_in,
                              void* d_out, int out_size, void* d_ws, size_t ws_size,
                              hipStream_t stream) {
    const float* logits  = (const float*)d_in[0];
    const float4* pboxes = (const float4*)d_in[1];
    const int4* tids     = (const int4*)d_in[2];
    const float4* tboxes = (const float4*)d_in[3];
    vfloat4* out = (vfloat4*)d_out;
    const int N = in_sizes[1] / 4;  // 14400 rows
    matcher_kernel<<<N / ROWS, NTHREADS, 0, stream>>>(logits, pboxes, tids, tboxes, out);
}